// Round 24
// baseline (42.126 us; speedup 1.0000x reference)
//
#include <hip/hip_runtime.h>
#include <stdint.h>

// Reference: pos += fl32(vel*dt); vel += fl32(fl32(-9.81)*fl32(0.01)); record pos.
// Exact emulation of the f32 scan via piecewise-constant-increment runs.
// r24 = r22 (r23 overlap regressed; reverted) with the vel chain converted to
// PURE INTEGER state: r22's residual ~20us ~ 70 links x 690cy matches a
// dependent f64 latency chain (~15 ops x ~40cy). Now: v = -g*ulp_k tracked as
// (k, g:int64); cg = shift-round(M*2^(E-k+24)); T = ceil(num/den) via f32
// estimate + int64 fixups (all <= 2^47); boundary steps = automatic 1-step
// links (num<=0 -> one f32 fadd + bit re-extract). f64 table (V,c,P) rebuilt
// from integers IN PARALLEL post-chain. Per-link bit-compare insurance (real
// fadd vs g+cg) -> proven ballot fallback on any mismatch.

static constexpr long long NSTEPS = 10000000LL;  // output rows
static constexpr long long NPOLY  = 4000000LL;   // polynomial cutover (even)
static constexpr long long NS     = 8000000LL;   // model/run cutover (even)
static constexpr long long KDIR   = 64;          // direct f32 steps
static constexpr int SEGCAP = 384;
static constexpr int RUNCAP = 96;

typedef float f4_native __attribute__((ext_vector_type(4)));

__device__ __forceinline__ bool same_binade_f32(float a, float b) {
    return (((__float_as_uint(a) ^ __float_as_uint(b)) & 0xFF800000u) == 0u);
}
__device__ __forceinline__ unsigned expfield(float v) {
    return (__float_as_uint(v) >> 23) & 0xFFu;
}
__device__ __forceinline__ float pow2f(int e) {
    return __uint_as_float((unsigned)(e + 127) << 23);
}
__device__ __forceinline__ double pow2d(int e) {
    return __longlong_as_double(((long long)(e + 1023)) << 52);
}
__device__ __forceinline__ float f32_from_kg(int k, long long g) {
    // value = -g * 2^(k-24), g in [2^23, 2^24)
    return __uint_as_float(0x80000000u | ((unsigned)(k + 126) << 23)
                           | ((unsigned)g & 0x7FFFFFu));
}
__device__ __forceinline__ void nt_store(float4* p, float4 v) {
    f4_native nv;
    nv.x = v.x; nv.y = v.y; nv.z = v.z; nv.w = v.w;
    __builtin_nontemporal_store(nv, (f4_native*)p);
}

__global__ __launch_bounds__(256, 4) void fused(
        const float* __restrict__ pos0, const float* __restrict__ vel0,
        float4* __restrict__ out, long long npairs)
{
    __shared__ int    s_m[SEGCAP + 1];
    __shared__ int    s_kI[SEGCAP + 1];
    __shared__ long long s_gI[SEGCAP + 1], s_cgI[SEGCAP];
    __shared__ double s_V[SEGCAP + 1], s_c[SEGCAP], s_P[SEGCAP];
    __shared__ float  s_Vf[SEGCAP], s_cdt[SEGCAP], s_Pf[SEGCAP];
    __shared__ int    r_n[RUNCAP];
    __shared__ double r_p[RUNCAP], r_i[RUNCAP];
    __shared__ float  r_pf[RUNCAP], r_if[RUNCAP];
    __shared__ int    s_nseg, s_bad, s_nrun;
    __shared__ long long s_mstop;
    __shared__ double s_v64, s_p64;

    const int tid  = threadIdx.x;
    const int lane = tid & 63;
    const int wv   = tid >> 6;

    const long long per = (npairs + (long long)gridDim.x - 1) / (long long)gridDim.x;
    const long long i0 = (long long)blockIdx.x * per;
    long long i1 = i0 + per; if (i1 > npairs) i1 = npairs;
    if (i0 >= npairs) return;
    const long long row0 = 2 * i0;
    const long long row1 = 2 * i1;
    const long long mstop = row1 < NSTEPS ? row1 : NSTEPS;

    const float dtf  = 0.01f;
    const float gdtf = __fmul_rn(-9.81f, dtf);
    const double dtd = (double)dtf, gcd = (double)gdtf, gdtd = gcd;
    const double p0y = (double)pos0[1], v0y = (double)vel0[1];

    // gc = -M * 2^E with M odd.
    long long Mg; int Eg;
    {
        unsigned gbits = __float_as_uint(gdtf);
        unsigned mant = (gbits & 0x7FFFFFu) | 0x800000u;
        int tz = __ffs((int)mant) - 1;
        Mg = (long long)(mant >> tz);
        Eg = (int)((gbits >> 23) & 0xFFu) - 127 - 23 + tz;
    }

    if (tid == 0) { s_nseg = 0; s_nrun = 0; s_mstop = 0; s_bad = 0; }
    __syncthreads();

    // ===== Phase A (wave 0, wave-uniform): INTEGER vel chain ================
    if (wv == 0 && row1 > NPOLY) {
        double V = v0y, P = p0y;
        for (int t = 0; t < (int)KDIR; ++t) {      // exact by definition
            const float vf = (float)V;
            P += dtd * V;
            V = (double)__fadd_rn(vf, gdtf);
        }
        if (lane == 0) { s_v64 = V; s_p64 = P; }

        bool bad = false;
        const float vf0 = (float)V;
        const unsigned ef0 = expfield(vf0);
        bad |= ((double)vf0 != V) | !(vf0 < 0.0f) | (ef0 == 0u) | (ef0 == 0xFFu);
        int k = (int)ef0 - 126;                     // |v| in [2^(k-1), 2^k)
        long long g = (long long)((__float_as_uint(vf0) & 0x7FFFFFu) | 0x800000u);
        long long m = KDIR;
        int nseg = 0;

        while (!bad && m < mstop && nseg < SEGCAP - 2) {
            const int s = k - 24 - Eg;              // q = M/2^s
            const long long rem = mstop - m;
            long long T = 0, cg = 0;
            if (s >= 2) {                           // non-tie, shift-round exact
                cg = (Mg + (1LL << (s - 1))) >> s;
                const long long num = (1LL << (24 + s)) - Mg - (g << s);
                if (num >= 1 && cg >= 1) {
                    const long long den = cg << s;
                    const float tf = __fdividef((float)num, (float)den);
                    T = (long long)tf + 1;          // target: ceil(num/den)
                    if (T < 1) T = 1;
                    for (int f = 0; f < 4 && T > 1 && (T - 1) * den >= num; ++f) --T;
                    for (int f = 0; f < 4 && T * den < num; ++f) ++T;
                    if (T > rem) T = rem;
                }
            }
            if (T >= 1) {                           // main segment
                // first-step bit-compare insurance (real fadd vs g+cg)
                const float vv = f32_from_kg(k, g);
                const float vn = __fadd_rn(vv, gdtf);
                long long ge = g + cg; int ke = k;
                if (ge >= (1LL << 24)) {            // may land exactly on edge
                    bad |= (ge != (1LL << 24));
                    ge = 1LL << 23; ke = k + 1;
                }
                bad |= (__float_as_uint(vn) != __float_as_uint(f32_from_kg(ke, ge)));

                if (lane == 0) { s_m[nseg] = (int)m; s_kI[nseg] = k;
                                 s_gI[nseg] = g; s_cgI[nseg] = cg; }
                ++nseg;
                g += T * cg; m += T;
                if (g >= (1LL << 24)) {             // exact edge landing
                    bad |= (g != (1LL << 24));
                    g = 1LL << 23; k += 1;
                }
                continue;
            }
            // 1-step direct link (boundary / tie / small-s): f32 fadd
            {
                const float vv = f32_from_kg(k, g);
                const float vb = __fadd_rn(vv, gdtf);
                const unsigned eb = expfield(vb);
                bad |= (eb == 0u) | (eb == 0xFFu) | !(vb < 0.0f);
                if (lane == 0) { s_m[nseg] = (int)m; s_kI[nseg] = k;
                                 s_gI[nseg] = g; s_cgI[nseg] = 0; }
                ++nseg;
                k = (int)eb - 126;
                g = (long long)((__float_as_uint(vb) & 0x7FFFFFu) | 0x800000u);
                m += 1;
            }
        }
        bad = bad | (m < mstop);
        if (lane == 0) {
            s_bad = bad ? 1 : 0;
            s_nseg = nseg;
            s_mstop = m;
            s_m[nseg] = 0x7fffffff;                 // sentinel
            s_kI[nseg] = k; s_gI[nseg] = g;         // final state (for last c)
        }
    }
    __syncthreads();

    // ===== Phase B: fallback — proven ballot staircase (inline P) ===========
    if (wv == 0 && s_bad && row1 > NPOLY) {
        double V = s_v64, P = s_p64;
        long long m = KDIR;
        int nseg = 0;
        while (m < mstop && nseg < SEGCAP) {
            const float vf  = (float)V;
            const float vn1 = __fadd_rn(vf, gdtf);
            const double c  = (double)vn1 - V;
            const long long rem = mstop - m;
            long long Lb = rem;
            const float cf = (float)c;
            const unsigned ef = expfield(vf);
            if (vf == 0.0f || ef == 0u) {
                Lb = 64;
            } else if (cf != 0.0f) {
                const int k = (int)ef - 126;
                float s = vf < 0.0f ? -1.0f : 1.0f;
                float B = ((vf < 0.0f) == (cf < 0.0f)) ? s * pow2f(k) : s * pow2f(k - 1);
                float r = __fdividef(B - vf, cf);
                if (r >= 0.0f && r < 4.0e9f) Lb = (long long)r + 1;
            }
            long long Lhi = Lb + 2;
            if (Lhi > rem) Lhi = rem;
            if (Lhi < 1) Lhi = 1;

            long long L = 1;
            {
                const long long candL = Lhi - 63 + (long long)lane;
                bool valid = false;
                if (candL >= 1) {
                    const double ve = V + (double)(candL - 1) * c;
                    const float vef = (float)ve;
                    const float vn2 = __fadd_rn(vef, gdtf);
                    valid = ((double)vef == ve)
                         && same_binade_f32(vef, vf)
                         && ((double)vn2 - ve == c);
                }
                const unsigned long long msk = __ballot(valid);
                if (msk) L = Lhi - 63 + (long long)(63 - __clzll(msk));
            }
            if (L < 1) L = 1;
            if (L > rem) L = rem;

            if (lane == 0) { s_m[nseg] = (int)m; s_V[nseg] = V; s_c[nseg] = c; s_P[nseg] = P; }
            ++nseg;
            P += dtd * ((double)L * V + c * ((double)L * (double)(L - 1) * 0.5));
            V += (double)L * c;
            m += L;
        }
        if (lane == 0) { s_nseg = nseg; s_mstop = m; s_m[nseg] = 0x7fffffff; }
    }
    __syncthreads();

    // ===== Phase V: rebuild f64 V, c from integers (parallel) ===============
    if (!s_bad && row1 > NPOLY && s_nseg > 0) {
        const int ns = s_nseg;
        for (int j = tid; j <= ns; j += 256)
            s_V[j] = -(double)s_gI[j] * pow2d(s_kI[j] - 24);
    }
    __syncthreads();
    if (!s_bad && row1 > NPOLY && s_nseg > 0) {
        const int ns = s_nseg;
        for (int j = tid; j < ns; j += 256) {
            s_c[j] = (s_cgI[j] > 0) ? -(double)s_cgI[j] * pow2d(s_kI[j] - 24)
                                    : (s_V[j + 1] - s_V[j]);
        }
    }
    __syncthreads();

    // ===== Phase P: serial P prefix (tid 0; ~45 segs) =======================
    if (!s_bad && row1 > NPOLY && s_nseg > 0 && tid == 0) {
        const int ns = s_nseg;
        double Pp = s_p64;
        for (int j = 0; j < ns; ++j) {
            s_P[j] = Pp;
            const long long mj = s_m[j];
            const long long me = (j + 1 < ns) ? (long long)s_m[j + 1] : s_mstop;
            const double len = (double)(me - mj);
            Pp += dtd * (len * s_V[j] + s_c[j] * (len * (len - 1.0) * 0.5));
        }
    }
    __syncthreads();

    // ===== Phase D (wave 0): pos run-chain from NS (single-window ballots) ==
    if (wv == 0 && row1 > NS && s_mstop >= NS && s_nseg > 0) {
        const int nseg = s_nseg;
        const long long mbuilt = s_mstop;
        int lo = 0, hi = nseg - 1;
        while (lo < hi) { int mid = (lo + hi + 1) >> 1;
                          if ((long long)s_m[mid] <= NS) lo = mid; else hi = mid - 1; }
        int jj = lo;
        const double t0 = (double)(NS - s_m[jj]);
        double vel = s_V[jj] + t0 * s_c[jj];
        double P2  = s_P[jj] + dtd * (t0 * s_V[jj] + s_c[jj] * (t0 * (t0 - 1.0) * 0.5));
        double pos = (double)(float)P2;
        long long n = NS;
        int nrun = 0;
        long long nend = (row1 < NSTEPS - 1) ? row1 : (NSTEPS - 1);
        if (nend > mbuilt) nend = mbuilt;
        while (n < nend && nrun < RUNCAP) {
            while (s_m[jj + 1] <= (int)n) ++jj;
            const double cv = s_c[jj];
            long long Lcap = (long long)s_m[jj + 1] - n;
            if (Lcap > mbuilt - n) Lcap = mbuilt - n;
            const long long rem = (NSTEPS - 1) - n;
            if (Lcap > rem) Lcap = rem;

            const float pf = (float)pos;
            const float vf2 = (float)vel;
            const float dstep = __fmul_rn(vf2, dtf);
            const float pn1 = __fadd_rn(pf, dstep);
            const double inc = (double)pn1 - pos;

            long long La = Lcap, Lc = Lcap;
            const float incf = (float)inc;
            const unsigned efp = expfield(pf);
            if (pf == 0.0f || efp == 0u) {
                La = 64;
            } else if (incf != 0.0f) {
                const int k = (int)efp - 126;
                float s = pf < 0.0f ? -1.0f : 1.0f;
                float B = ((pf < 0.0f) == (incf < 0.0f)) ? s * pow2f(k) : s * pow2f(k - 1);
                float r = __fdividef(B - pf, incf);
                if (r >= 0.0f && r < 4.0e9f) { La = (long long)r - 1; if (La < 0) La = 0; }
            }
            const double dd = cv * dtd;
            if (dd != 0.0 && pf != 0.0f && efp != 0u) {
                const int k = (int)efp - 126;
                if (k - 24 > -126) {
                    const float ulpf = pow2f(k - 24);
                    const double d0 = (double)dstep;
                    const double T = inc + (dd < 0.0 ? -0.5 : 0.5) * (double)ulpf;
                    float r = __fdividef((float)(T - d0), (float)dd);
                    if (r >= 0.0f && r < 4.0e9f) { Lc = (long long)r + 2; if (Lc < 1) Lc = 1; }
                }
            }
            long long Lhi = La < Lc ? La : Lc;
            Lhi += 3;
            if (Lhi > Lcap) Lhi = Lcap;
            if (Lhi < 1) Lhi = 1;

            long long L = 1;
            {
                const long long candL = Lhi - 63 + (long long)lane;
                bool valid = false;
                if (candL >= 1) {
                    const double pe = pos + (double)(candL - 1) * inc;
                    const double ve = vel + (double)(candL - 1) * cv;
                    const float pef = (float)pe;
                    const float vef = (float)ve;
                    const float d2  = __fmul_rn(vef, dtf);
                    const float pn2 = __fadd_rn(pef, d2);
                    valid = ((double)pef == pe)
                         && same_binade_f32(pef, pf)
                         && ((double)vef == ve)
                         && ((double)pn2 - pe == inc);
                }
                const unsigned long long msk = __ballot(valid);
                if (msk) L = Lhi - 63 + (long long)(63 - __clzll(msk));
            }
            if (L < 1) L = 1;
            if (L > Lcap) L = Lcap;
            if (L < 1) L = 1;

            if (lane == 0) { r_n[nrun] = (int)n; r_p[nrun] = pos; r_i[nrun] = inc; }
            ++nrun;
            pos += (double)L * inc;
            vel += (double)L * cv;
            n += L;
        }
        if (lane == 0) s_nrun = nrun;
    }
    __syncthreads();

    // ===== f32 mirror tables ================================================
    {
        const int nseg = s_nseg, nrun = s_nrun;
        for (int i = tid; i < nseg; i += 256) {
            s_Vf[i]  = (float)s_V[i];
            s_cdt[i] = (float)(dtd * s_c[i]);
            s_Pf[i]  = (float)s_P[i];
        }
        for (int i = tid; i < nrun; i += 256) {
            r_pf[i] = (float)r_p[i];
            r_if[i] = (float)r_i[i];
        }
    }
    __syncthreads();

    // ===== Fill with per-block fast paths (nontemporal stores) ==============
    const int nseg = s_nseg;
    const int nrun = s_nrun;
    const float pxf = pos0[0];
    const float cxf = __fmul_rn(vel0[0], dtf);
    const float pyf = (float)p0y;
    const float vyf = (float)v0y;
    const float q2f = (float)(dtd * gdtd);       // dt*gc

    const long long ii = i0 + tid;
    if (ii >= i1) return;

    // Classify block: 0 poly, 1 single-segment, 2 single-run, 3 general.
    int mode = 3, jf = 0, rf = 0;
    if (row1 <= NPOLY) {
        mode = 0;
    } else if (row0 >= NS && nrun > 0) {
        int rlo = 0, rhi = nrun - 1;
        const int t0 = (int)row0;
        while (rlo < rhi) { int mid = (rlo + rhi + 1) >> 1; if (r_n[mid] <= t0) rlo = mid; else rhi = mid - 1; }
        rf = rlo;
        if (rf + 1 >= nrun || (long long)r_n[rf + 1] >= row1) mode = 2;
    } else if (row0 >= NPOLY && row1 <= NS && nseg > 0) {
        int lo = 0, hi = nseg - 1;
        const int t0 = (int)row0;
        while (lo < hi) { int mid = (lo + hi + 1) >> 1; if (s_m[mid] <= t0) lo = mid; else hi = mid - 1; }
        jf = lo;
        if ((long long)s_m[jf + 1] >= row1) mode = 1;
    }

    if (mode == 0) {            // y = A + B*m + C*m^2 (registers only)
        const float C = 0.5f * q2f;
        const float B = dtf * vyf - C;
        const float A = pyf;
        for (long long i = ii; i < i1; i += blockDim.x) {
            const float mf0 = (float)(2 * i), mf1 = mf0 + 1.0f;
            float4 o;
            o.x = fmaf(mf0, cxf, pxf);
            o.z = fmaf(mf1, cxf, pxf);
            o.y = fmaf(mf0, fmaf(mf0, C, B), A);
            o.w = fmaf(mf1, fmaf(mf1, C, B), A);
            nt_store(&out[i], o);
        }
    } else if (mode == 1) {     // single segment: quadratic in t = m - mj
        const float C = 0.5f * s_cdt[jf];
        const float B = dtf * s_Vf[jf] - C;
        const float A = s_Pf[jf];
        const int mj = s_m[jf];
        for (long long i = ii; i < i1; i += blockDim.x) {
            const float t0 = (float)(int)(2 * i - mj), t1 = t0 + 1.0f;
            const float mf0 = (float)(2 * i), mf1 = mf0 + 1.0f;
            float4 o;
            o.x = fmaf(mf0, cxf, pxf);
            o.z = fmaf(mf1, cxf, pxf);
            o.y = fmaf(t0, fmaf(t0, C, B), A);
            o.w = fmaf(t1, fmaf(t1, C, B), A);
            nt_store(&out[i], o);
        }
    } else if (mode == 2) {     // single run: linear in t
        const float A = r_pf[rf], Bv = r_if[rf];
        const int rn0 = r_n[rf];
        for (long long i = ii; i < i1; i += blockDim.x) {
            const float t0 = (float)(int)(2 * i - rn0), t1 = t0 + 1.0f;
            const float mf0 = (float)(2 * i), mf1 = mf0 + 1.0f;
            float4 o;
            o.x = fmaf(mf0, cxf, pxf);
            o.z = fmaf(mf1, cxf, pxf);
            o.y = fmaf(t0, Bv, A);
            o.w = fmaf(t1, Bv, A);
            nt_store(&out[i], o);
        }
    } else {                    // general (boundary blocks)
        int j = 0, r = 0;
        if (nseg > 0) {
            const int t0 = (int)(2 * ii);
            int lo = 0, hi = nseg - 1;
            while (lo < hi) { int mid = (lo + hi + 1) >> 1; if (s_m[mid] <= t0) lo = mid; else hi = mid - 1; }
            j = lo;
            if (nrun > 0) {
                int rlo = 0, rhi = nrun - 1;
                while (rlo < rhi) { int mid = (rlo + rhi + 1) >> 1; if (r_n[mid] <= t0) rlo = mid; else rhi = mid - 1; }
                r = rlo;
            }
        }
        for (long long i = ii; i < i1; i += blockDim.x) {
            const long long m0 = 2 * i, m1 = m0 + 1;
            const float mf0 = (float)m0, mf1 = (float)m1;
            float4 o;
            o.x = fmaf(mf0, cxf, pxf);
            o.z = fmaf(mf1, cxf, pxf);
            const int t0 = (int)m0;
            if (m1 < NPOLY) {
                const float C = 0.5f * q2f;
                const float B = dtf * vyf - C;
                o.y = fmaf(mf0, fmaf(mf0, C, B), pyf);
                o.w = fmaf(mf1, fmaf(mf1, C, B), pyf);
            } else if (m1 < NS || nrun <= 0) {
                while (s_m[j + 1] <= t0) ++j;
                float t = (float)(int)(m0 - s_m[j]);
                o.y = s_Pf[j] + dtf * (t * s_Vf[j]) + s_cdt[j] * (t * (t - 1.0f) * 0.5f);
                const int j1 = (s_m[j + 1] <= (int)m1) ? j + 1 : j;
                t = (float)(int)(m1 - s_m[j1]);
                o.w = s_Pf[j1] + dtf * (t * s_Vf[j1]) + s_cdt[j1] * (t * (t - 1.0f) * 0.5f);
            } else {
                while (r + 1 < nrun && r_n[r + 1] <= t0) ++r;
                o.y = r_pf[r] + (float)(int)(m0 - r_n[r]) * r_if[r];
                const int r1 = (r + 1 < nrun && r_n[r + 1] <= (int)m1) ? r + 1 : r;
                o.w = r_pf[r1] + (float)(int)(m1 - r_n[r1]) * r_if[r1];
            }
            nt_store(&out[i], o);
        }
    }
}

extern "C" void kernel_launch(void* const* d_in, const int* in_sizes, int n_in,
                              void* d_out, int out_size, void* d_ws, size_t ws_size,
                              hipStream_t stream) {
    // Inputs: [0] ball_mass (unused), [1] initial_position[2], [2] initial_velocity[2].
    const float* pos0 = (const float*)d_in[1];
    const float* vel0 = (const float*)d_in[2];

    const long long npairs = (long long)out_size / 4;  // 5,000,000 float4s
    fused<<<1024, 256, 0, stream>>>(pos0, vel0, (float4*)d_out, npairs);
}

// Round 25
// 35.318 us; speedup vs baseline: 1.1928x; 1.1928x over previous
//
#include <hip/hip_runtime.h>
#include <stdint.h>

// Reference: pos += fl32(vel*dt); vel += fl32(fl32(-9.81)*fl32(0.01)); record pos.
// Exact emulation of the f32 scan via piecewise-constant-increment runs.
// r25 = r22 RESTORED (proven best: 34.93us). r23 (chain/fill overlap) -> 38.1,
// r24 (integer chain) -> 42.1 — both regressed; this configuration is the
// empirical optimum: fused single launch, wave-uniform ballot-T staircase,
// deferred P prefix, NPOLY=4e6 / NS=8e6 regions, per-block fast-mode fills,
// nontemporal stores, grid 1024 x lb(256,4).

static constexpr long long NSTEPS = 10000000LL;  // output rows
static constexpr long long NPOLY  = 4000000LL;   // polynomial cutover (even)
static constexpr long long NS     = 8000000LL;   // model/run cutover (even)
static constexpr long long KDIR   = 64;          // direct f32 steps
static constexpr int SEGCAP = 384;
static constexpr int RUNCAP = 96;

typedef float f4_native __attribute__((ext_vector_type(4)));

__device__ __forceinline__ bool same_binade_f32(float a, float b) {
    return (((__float_as_uint(a) ^ __float_as_uint(b)) & 0xFF800000u) == 0u);
}
__device__ __forceinline__ unsigned expfield(float v) {
    return (__float_as_uint(v) >> 23) & 0xFFu;
}
__device__ __forceinline__ float pow2f(int e) {
    return __uint_as_float((unsigned)(e + 127) << 23);
}
__device__ __forceinline__ double pow2d(int e) {
    return __longlong_as_double(((long long)(e + 1023)) << 52);
}
__device__ __forceinline__ void nt_store(float4* p, float4 v) {
    f4_native nv;
    nv.x = v.x; nv.y = v.y; nv.z = v.z; nv.w = v.w;
    __builtin_nontemporal_store(nv, (f4_native*)p);
}

__global__ __launch_bounds__(256, 4) void fused(
        const float* __restrict__ pos0, const float* __restrict__ vel0,
        float4* __restrict__ out, long long npairs)
{
    __shared__ int    s_m[SEGCAP + 1];
    __shared__ double s_V[SEGCAP], s_c[SEGCAP], s_P[SEGCAP], s_dP[SEGCAP];
    __shared__ float  s_Vf[SEGCAP], s_cdt[SEGCAP], s_Pf[SEGCAP];
    __shared__ int    r_n[RUNCAP];
    __shared__ double r_p[RUNCAP], r_i[RUNCAP];
    __shared__ float  r_pf[RUNCAP], r_if[RUNCAP];
    __shared__ int    s_nseg, s_bad, s_nrun;
    __shared__ long long s_mstop;
    __shared__ double s_v64, s_p64;

    const int tid  = threadIdx.x;
    const int lane = tid & 63;
    const int wv   = tid >> 6;

    const long long per = (npairs + (long long)gridDim.x - 1) / (long long)gridDim.x;
    const long long i0 = (long long)blockIdx.x * per;
    long long i1 = i0 + per; if (i1 > npairs) i1 = npairs;
    if (i0 >= npairs) return;
    const long long row0 = 2 * i0;
    const long long row1 = 2 * i1;
    const long long mstop = row1 < NSTEPS ? row1 : NSTEPS;

    const float dtf  = 0.01f;
    const float gdtf = __fmul_rn(-9.81f, dtf);
    const double dtd = (double)dtf, gcd = (double)gdtf, gdtd = gcd;
    const double p0y = (double)pos0[1], v0y = (double)vel0[1];

    // Unique tie binade: gc = -M*2^E (M odd); tie iff k = E+25.
    int k_tie;
    {
        unsigned gbits = __float_as_uint(gdtf);
        unsigned mant = (gbits & 0x7FFFFFu) | 0x800000u;
        int tz = __ffs((int)mant) - 1;
        int E = (int)((gbits >> 23) & 0xFFu) - 127 - 23 + tz;
        k_tie = E + 25;
    }

    if (tid == 0) { s_nseg = 0; s_nrun = 0; s_mstop = 0; s_bad = 0; }
    __syncthreads();

    // ===== Phase A (wave 0, WAVE-UNIFORM): direct-64 + ballot-T staircase ===
    if (wv == 0 && row1 > NPOLY) {
        double V = v0y, P = p0y;
        for (int t = 0; t < (int)KDIR; ++t) {      // exact by definition
            const float vf = (float)V;
            P += dtd * V;
            V = (double)__fadd_rn(vf, gdtf);
        }
        if (lane == 0) { s_v64 = V; s_p64 = P; }

        bool bad = false;
        long long m = KDIR;
        int nseg = 0;
        while (m < mstop && nseg < SEGCAP - 2) {
            const float vf = (float)V;
            const unsigned ef = expfield(vf);
            bad = bad | ((double)vf != V) | !(vf < 0.0f) | (ef == 0u) | (ef == 0xFFu);
            if (bad) break;                         // wave-uniform
            const int k = (int)ef - 126;            // |V| in [2^(k-1), 2^k)
            const float vn1 = __fadd_rn(vf, gdtf);
            const double c = (double)vn1 - V;       // exact 1-step increment
            if (!(c < 0.0)) { bad = true; break; }
            const long long rem = mstop - m;

            long long T = 1;                        // 1-step always exact
            if (k != k_tie) {
                const double inv_ulp = pow2d(24 - k);
                const double g  = -V * inv_ulp;     // exact integer [2^23,2^24)
                const double q  = -gcd * inv_ulp;   // exact dyadic, > 0
                const double cg = -c * inv_ulp;     // exact integer >= 1
                const double lim = 16777216.0;
                float t0f = __fdividef((float)(lim - g - q), (float)cg);
                const long long Th = (long long)t0f;
                // One ballot: highest Tc in [Th-31, Th+32] with the exact
                // monotone stay-condition. Empty => T=1 (boundary step).
                const long long Tc = Th - 31 + (long long)lane;
                const bool valid = (Tc >= 1) && (Tc <= rem)
                                && (g + (double)(Tc - 1) * cg + q < lim);
                const unsigned long long msk = __ballot(valid);
                if (msk) T = Th - 31 + (long long)(63 - __clzll(msk));
                else     T = (Th - 31 > rem) ? rem : 1;
                if (T < 1) T = 1;
                if (T > rem) T = rem;
            }
            if (lane == 0) { s_m[nseg] = (int)m; s_V[nseg] = V; s_c[nseg] = c; }
            ++nseg;
            V += (double)T * c;                     // exact dyadics
            m += T;
        }
        bad = bad | (m < mstop);
        if (lane == 0) {
            s_bad = bad ? 1 : 0;
            s_nseg = nseg;
            s_mstop = m;
            s_m[nseg] = 0x7fffffff;                 // sentinel
        }
    }
    __syncthreads();

    // ===== Phase B: fallback — proven ballot staircase (inline P) ===========
    if (wv == 0 && s_bad && row1 > NPOLY) {
        double V = s_v64, P = s_p64;
        long long m = KDIR;
        int nseg = 0;
        while (m < mstop && nseg < SEGCAP) {
            const float vf  = (float)V;
            const float vn1 = __fadd_rn(vf, gdtf);
            const double c  = (double)vn1 - V;
            const long long rem = mstop - m;
            long long Lb = rem;
            const float cf = (float)c;
            const unsigned ef = expfield(vf);
            if (vf == 0.0f || ef == 0u) {
                Lb = 64;
            } else if (cf != 0.0f) {
                const int k = (int)ef - 126;
                float s = vf < 0.0f ? -1.0f : 1.0f;
                float B = ((vf < 0.0f) == (cf < 0.0f)) ? s * pow2f(k) : s * pow2f(k - 1);
                float r = __fdividef(B - vf, cf);
                if (r >= 0.0f && r < 4.0e9f) Lb = (long long)r + 1;
            }
            long long Lhi = Lb + 2;
            if (Lhi > rem) Lhi = rem;
            if (Lhi < 1) Lhi = 1;

            long long L = 1;
            {
                const long long candL = Lhi - 63 + (long long)lane;
                bool valid = false;
                if (candL >= 1) {
                    const double ve = V + (double)(candL - 1) * c;
                    const float vef = (float)ve;
                    const float vn2 = __fadd_rn(vef, gdtf);
                    valid = ((double)vef == ve)
                         && same_binade_f32(vef, vf)
                         && ((double)vn2 - ve == c);
                }
                const unsigned long long msk = __ballot(valid);
                if (msk) L = Lhi - 63 + (long long)(63 - __clzll(msk));
            }
            if (L < 1) L = 1;
            if (L > rem) L = rem;

            if (lane == 0) { s_m[nseg] = (int)m; s_V[nseg] = V; s_c[nseg] = c; s_P[nseg] = P; }
            ++nseg;
            P += dtd * ((double)L * V + c * ((double)L * (double)(L - 1) * 0.5));
            V += (double)L * c;
            m += L;
        }
        if (lane == 0) { s_nseg = nseg; s_mstop = m; s_m[nseg] = 0x7fffffff; }
    }
    __syncthreads();

    // ===== Phase P: deferred P (parallel terms + tid0 prefix) ===============
    if (!s_bad && row1 > NPOLY && s_nseg > 0) {
        const int nseg = s_nseg;
        for (int j = tid; j < nseg; j += 256) {
            const long long mj = s_m[j];
            const long long me = (j + 1 < nseg) ? (long long)s_m[j + 1] : s_mstop;
            const double len = (double)(me - mj);
            s_dP[j] = dtd * (len * s_V[j] + s_c[j] * (len * (len - 1.0) * 0.5));
        }
        __syncthreads();
        if (tid == 0) {
            double P = s_p64;
            for (int j = 0; j < nseg; ++j) { s_P[j] = P; P += s_dP[j]; }
        }
    }
    __syncthreads();

    // ===== Phase D (wave 0): pos run-chain from NS (single-window ballots) ==
    if (wv == 0 && row1 > NS && s_mstop >= NS && s_nseg > 0) {
        const int nseg = s_nseg;
        const long long mbuilt = s_mstop;
        int lo = 0, hi = nseg - 1;
        while (lo < hi) { int mid = (lo + hi + 1) >> 1;
                          if ((long long)s_m[mid] <= NS) lo = mid; else hi = mid - 1; }
        int jj = lo;
        const double t0 = (double)(NS - s_m[jj]);
        double vel = s_V[jj] + t0 * s_c[jj];
        double P2  = s_P[jj] + dtd * (t0 * s_V[jj] + s_c[jj] * (t0 * (t0 - 1.0) * 0.5));
        double pos = (double)(float)P2;
        long long n = NS;
        int nrun = 0;
        long long nend = (row1 < NSTEPS - 1) ? row1 : (NSTEPS - 1);
        if (nend > mbuilt) nend = mbuilt;
        while (n < nend && nrun < RUNCAP) {
            while (s_m[jj + 1] <= (int)n) ++jj;
            const double cv = s_c[jj];
            long long Lcap = (long long)s_m[jj + 1] - n;
            if (Lcap > mbuilt - n) Lcap = mbuilt - n;
            const long long rem = (NSTEPS - 1) - n;
            if (Lcap > rem) Lcap = rem;

            const float pf = (float)pos;
            const float vf2 = (float)vel;
            const float dstep = __fmul_rn(vf2, dtf);
            const float pn1 = __fadd_rn(pf, dstep);
            const double inc = (double)pn1 - pos;

            long long La = Lcap, Lc = Lcap;
            const float incf = (float)inc;
            const unsigned efp = expfield(pf);
            if (pf == 0.0f || efp == 0u) {
                La = 64;
            } else if (incf != 0.0f) {
                const int k = (int)efp - 126;
                float s = pf < 0.0f ? -1.0f : 1.0f;
                float B = ((pf < 0.0f) == (incf < 0.0f)) ? s * pow2f(k) : s * pow2f(k - 1);
                float r = __fdividef(B - pf, incf);
                if (r >= 0.0f && r < 4.0e9f) { La = (long long)r - 1; if (La < 0) La = 0; }
            }
            const double dd = cv * dtd;
            if (dd != 0.0 && pf != 0.0f && efp != 0u) {
                const int k = (int)efp - 126;
                if (k - 24 > -126) {
                    const float ulpf = pow2f(k - 24);
                    const double d0 = (double)dstep;
                    const double T = inc + (dd < 0.0 ? -0.5 : 0.5) * (double)ulpf;
                    float r = __fdividef((float)(T - d0), (float)dd);
                    if (r >= 0.0f && r < 4.0e9f) { Lc = (long long)r + 2; if (Lc < 1) Lc = 1; }
                }
            }
            long long Lhi = La < Lc ? La : Lc;
            Lhi += 3;
            if (Lhi > Lcap) Lhi = Lcap;
            if (Lhi < 1) Lhi = 1;

            long long L = 1;
            {
                const long long candL = Lhi - 63 + (long long)lane;
                bool valid = false;
                if (candL >= 1) {
                    const double pe = pos + (double)(candL - 1) * inc;
                    const double ve = vel + (double)(candL - 1) * cv;
                    const float pef = (float)pe;
                    const float vef = (float)ve;
                    const float d2  = __fmul_rn(vef, dtf);
                    const float pn2 = __fadd_rn(pef, d2);
                    valid = ((double)pef == pe)
                         && same_binade_f32(pef, pf)
                         && ((double)vef == ve)
                         && ((double)pn2 - pe == inc);
                }
                const unsigned long long msk = __ballot(valid);
                if (msk) L = Lhi - 63 + (long long)(63 - __clzll(msk));
            }
            if (L < 1) L = 1;
            if (L > Lcap) L = Lcap;
            if (L < 1) L = 1;

            if (lane == 0) { r_n[nrun] = (int)n; r_p[nrun] = pos; r_i[nrun] = inc; }
            ++nrun;
            pos += (double)L * inc;
            vel += (double)L * cv;
            n += L;
        }
        if (lane == 0) s_nrun = nrun;
    }
    __syncthreads();

    // ===== f32 mirror tables ================================================
    {
        const int nseg = s_nseg, nrun = s_nrun;
        for (int i = tid; i < nseg; i += 256) {
            s_Vf[i]  = (float)s_V[i];
            s_cdt[i] = (float)(dtd * s_c[i]);
            s_Pf[i]  = (float)s_P[i];
        }
        for (int i = tid; i < nrun; i += 256) {
            r_pf[i] = (float)r_p[i];
            r_if[i] = (float)r_i[i];
        }
    }
    __syncthreads();

    // ===== Fill with per-block fast paths (nontemporal stores) ==============
    const int nseg = s_nseg;
    const int nrun = s_nrun;
    const float pxf = pos0[0];
    const float cxf = __fmul_rn(vel0[0], dtf);
    const float pyf = (float)p0y;
    const float vyf = (float)v0y;
    const float q2f = (float)(dtd * gdtd);       // dt*gc

    const long long ii = i0 + tid;
    if (ii >= i1) return;

    // Classify block: 0 poly, 1 single-segment, 2 single-run, 3 general.
    int mode = 3, jf = 0, rf = 0;
    if (row1 <= NPOLY) {
        mode = 0;
    } else if (row0 >= NS && nrun > 0) {
        int rlo = 0, rhi = nrun - 1;
        const int t0 = (int)row0;
        while (rlo < rhi) { int mid = (rlo + rhi + 1) >> 1; if (r_n[mid] <= t0) rlo = mid; else rhi = mid - 1; }
        rf = rlo;
        if (rf + 1 >= nrun || (long long)r_n[rf + 1] >= row1) mode = 2;
    } else if (row0 >= NPOLY && row1 <= NS && nseg > 0) {
        int lo = 0, hi = nseg - 1;
        const int t0 = (int)row0;
        while (lo < hi) { int mid = (lo + hi + 1) >> 1; if (s_m[mid] <= t0) lo = mid; else hi = mid - 1; }
        jf = lo;
        if ((long long)s_m[jf + 1] >= row1) mode = 1;
    }

    if (mode == 0) {            // y = A + B*m + C*m^2 (registers only)
        const float C = 0.5f * q2f;
        const float B = dtf * vyf - C;
        const float A = pyf;
        for (long long i = ii; i < i1; i += blockDim.x) {
            const float mf0 = (float)(2 * i), mf1 = mf0 + 1.0f;
            float4 o;
            o.x = fmaf(mf0, cxf, pxf);
            o.z = fmaf(mf1, cxf, pxf);
            o.y = fmaf(mf0, fmaf(mf0, C, B), A);
            o.w = fmaf(mf1, fmaf(mf1, C, B), A);
            nt_store(&out[i], o);
        }
    } else if (mode == 1) {     // single segment: quadratic in t = m - mj
        const float C = 0.5f * s_cdt[jf];
        const float B = dtf * s_Vf[jf] - C;
        const float A = s_Pf[jf];
        const int mj = s_m[jf];
        for (long long i = ii; i < i1; i += blockDim.x) {
            const float t0 = (float)(int)(2 * i - mj), t1 = t0 + 1.0f;
            const float mf0 = (float)(2 * i), mf1 = mf0 + 1.0f;
            float4 o;
            o.x = fmaf(mf0, cxf, pxf);
            o.z = fmaf(mf1, cxf, pxf);
            o.y = fmaf(t0, fmaf(t0, C, B), A);
            o.w = fmaf(t1, fmaf(t1, C, B), A);
            nt_store(&out[i], o);
        }
    } else if (mode == 2) {     // single run: linear in t
        const float A = r_pf[rf], Bv = r_if[rf];
        const int rn0 = r_n[rf];
        for (long long i = ii; i < i1; i += blockDim.x) {
            const float t0 = (float)(int)(2 * i - rn0), t1 = t0 + 1.0f;
            const float mf0 = (float)(2 * i), mf1 = mf0 + 1.0f;
            float4 o;
            o.x = fmaf(mf0, cxf, pxf);
            o.z = fmaf(mf1, cxf, pxf);
            o.y = fmaf(t0, Bv, A);
            o.w = fmaf(t1, Bv, A);
            nt_store(&out[i], o);
        }
    } else {                    // general (boundary blocks)
        int j = 0, r = 0;
        if (nseg > 0) {
            const int t0 = (int)(2 * ii);
            int lo = 0, hi = nseg - 1;
            while (lo < hi) { int mid = (lo + hi + 1) >> 1; if (s_m[mid] <= t0) lo = mid; else hi = mid - 1; }
            j = lo;
            if (nrun > 0) {
                int rlo = 0, rhi = nrun - 1;
                while (rlo < rhi) { int mid = (rlo + rhi + 1) >> 1; if (r_n[mid] <= t0) rlo = mid; else rhi = mid - 1; }
                r = rlo;
            }
        }
        for (long long i = ii; i < i1; i += blockDim.x) {
            const long long m0 = 2 * i, m1 = m0 + 1;
            const float mf0 = (float)m0, mf1 = (float)m1;
            float4 o;
            o.x = fmaf(mf0, cxf, pxf);
            o.z = fmaf(mf1, cxf, pxf);
            const int t0 = (int)m0;
            if (m1 < NPOLY) {
                const float C = 0.5f * q2f;
                const float B = dtf * vyf - C;
                o.y = fmaf(mf0, fmaf(mf0, C, B), pyf);
                o.w = fmaf(mf1, fmaf(mf1, C, B), pyf);
            } else if (m1 < NS || nrun <= 0) {
                while (s_m[j + 1] <= t0) ++j;
                float t = (float)(int)(m0 - s_m[j]);
                o.y = s_Pf[j] + dtf * (t * s_Vf[j]) + s_cdt[j] * (t * (t - 1.0f) * 0.5f);
                const int j1 = (s_m[j + 1] <= (int)m1) ? j + 1 : j;
                t = (float)(int)(m1 - s_m[j1]);
                o.w = s_Pf[j1] + dtf * (t * s_Vf[j1]) + s_cdt[j1] * (t * (t - 1.0f) * 0.5f);
            } else {
                while (r + 1 < nrun && r_n[r + 1] <= t0) ++r;
                o.y = r_pf[r] + (float)(int)(m0 - r_n[r]) * r_if[r];
                const int r1 = (r + 1 < nrun && r_n[r + 1] <= (int)m1) ? r + 1 : r;
                o.w = r_pf[r1] + (float)(int)(m1 - r_n[r1]) * r_if[r1];
            }
            nt_store(&out[i], o);
        }
    }
}

extern "C" void kernel_launch(void* const* d_in, const int* in_sizes, int n_in,
                              void* d_out, int out_size, void* d_ws, size_t ws_size,
                              hipStream_t stream) {
    // Inputs: [0] ball_mass (unused), [1] initial_position[2], [2] initial_velocity[2].
    const float* pos0 = (const float*)d_in[1];
    const float* vel0 = (const float*)d_in[2];

    const long long npairs = (long long)out_size / 4;  // 5,000,000 float4s
    fused<<<1024, 256, 0, stream>>>(pos0, vel0, (float4*)d_out, npairs);
}